// Round 12
// baseline (345.232 us; speedup 1.0000x reference)
//
#include <hip/hip_runtime.h>

#define IN_DIM 128
#define HID 64
#define ODIM 40
#define BSH 7
#define BSZ 128        // nodes per bucket
#define NBMAX 1024     // max buckets (n <= 131072)
#define NBLK 256       // partition blocks (1 per CU)
#define NBLKSH 8       // log2(NBLK)
#define SCH 2048       // scan chunk: 256 thr x 8 elems

// ================= pass 1: per-(block,bucket) histogram =================

__global__ __launch_bounds__(256) void k_hist(const int* __restrict__ dst,
                                              int* __restrict__ histM, int e, int nb) {
    __shared__ int hist[NBMAX];
    const int t = threadIdx.x;
    const int blk = blockIdx.x;
    for (int i = t; i < nb; i += 256) hist[i] = 0;
    __syncthreads();
    const int chunk = (e + NBLK - 1) / NBLK;
    const int beg = blk * chunk, end = min(beg + chunk, e);
    for (int i = beg + t; i < end; i += 256)
        atomicAdd(&hist[dst[i] >> BSH], 1);
    __syncthreads();
    for (int i = t; i < nb; i += 256) histM[i * NBLK + blk] = hist[i];
}

// ================= pass 2: hierarchical exclusive scan of histM =================

__global__ __launch_bounds__(256) void k_s1(const int* __restrict__ histM,
                                            int* __restrict__ csum, int total) {
    __shared__ int red[256];
    const int t = threadIdx.x;
    const int base = blockIdx.x * SCH + t * 8;
    int s = 0;
#pragma unroll
    for (int j = 0; j < 8; ++j) {
        int idx = base + j;
        if (idx < total) s += histM[idx];
    }
    red[t] = s;
    __syncthreads();
    for (int off = 128; off > 0; off >>= 1) {
        if (t < off) red[t] += red[t + off];
        __syncthreads();
    }
    if (t == 0) csum[blockIdx.x] = red[0];
}

__global__ __launch_bounds__(256) void k_s2(int* __restrict__ csum, int nchunks,
                                            int* __restrict__ rowptr, int n, int e) {
    __shared__ int tmp[256];
    const int tid = threadIdx.x;
    int v = (tid < nchunks) ? csum[tid] : 0;
    tmp[tid] = v;
    __syncthreads();
    for (int off = 1; off < 256; off <<= 1) {
        int t_ = (tid >= off) ? tmp[tid - off] : 0;
        __syncthreads();
        tmp[tid] += t_;
        __syncthreads();
    }
    if (tid < nchunks) csum[tid] = tmp[tid] - v;  // exclusive
    if (tid == 0) rowptr[n] = e;
}

__global__ __launch_bounds__(256) void k_s3(const int* __restrict__ histM,
                                            const int* __restrict__ csum,
                                            int* __restrict__ offM,
                                            int* __restrict__ bbase, int total) {
    __shared__ int tsum[256];
    const int t = threadIdx.x;
    const int base = blockIdx.x * SCH + t * 8;
    int v[8];
#pragma unroll
    for (int j = 0; j < 8; ++j) {
        int idx = base + j;
        v[j] = (idx < total) ? histM[idx] : 0;
    }
    int pre[9];
    pre[0] = 0;
#pragma unroll
    for (int j = 0; j < 8; ++j) pre[j + 1] = pre[j] + v[j];
    tsum[t] = pre[8];
    __syncthreads();
    for (int off = 1; off < 256; off <<= 1) {
        int tv = (t >= off) ? tsum[t - off] : 0;
        __syncthreads();
        tsum[t] += tv;
        __syncthreads();
    }
    const int b0 = csum[blockIdx.x] + (tsum[t] - pre[8]);
#pragma unroll
    for (int j = 0; j < 8; ++j) {
        int idx = base + j;
        if (idx < total) {
            int val = b0 + pre[j];
            offM[idx] = val;
            if ((idx & (NBLK - 1)) == 0) bbase[idx >> NBLKSH] = val;
        }
    }
}

// ================= pass 3: scatter via LDS cursors (no global atomics) =================
// packed: src | (local_dst << 20)   (src < 2^20, local_dst < 128)

__global__ __launch_bounds__(256) void k_bscatter2(const int* __restrict__ src,
                                                   const int* __restrict__ dst,
                                                   const int* __restrict__ offM,
                                                   int* __restrict__ ebuf, int e, int nb) {
    __shared__ int lcur[NBMAX];
    const int t = threadIdx.x;
    const int blk = blockIdx.x;
    for (int i = t; i < nb; i += 256) lcur[i] = offM[i * NBLK + blk];
    __syncthreads();
    const int chunk = (e + NBLK - 1) / NBLK;
    const int beg = blk * chunk, end = min(beg + chunk, e);
    for (int i = beg + t; i < end; i += 256) {
        int s = src[i], d = dst[i];
        int b = d >> BSH;
        int p = atomicAdd(&lcur[b], 1);  // LDS atomic: block-local contention only
        ebuf[p] = s | ((d & (BSZ - 1)) << 20);
    }
}

// ================= per-bucket counting sort -> CSR (+rowptr, dinv) =================

__global__ __launch_bounds__(256) void k_bsort(const int* __restrict__ ebuf,
                                               const int* __restrict__ bbase,
                                               int* __restrict__ esrc,
                                               int* __restrict__ rowptr,
                                               float* __restrict__ dinv,
                                               int n, int nb, int e) {
    __shared__ int hist[BSZ];
    __shared__ int sc[BSZ];
    __shared__ int hoff[BSZ];
    const int t = threadIdx.x;
    const int b = blockIdx.x;
    const int node0 = b << BSH;
    if (t < BSZ) hist[t] = 0;
    __syncthreads();
    const int beg = bbase[b];
    const int end = (b + 1 < nb) ? bbase[b + 1] : e;
    for (int i = beg + t; i < end; i += 256)
        atomicAdd(&hist[ebuf[i] >> 20], 1);
    __syncthreads();
    int v = (t < BSZ) ? hist[t] : 0;
    if (t < BSZ) sc[t] = v;
    __syncthreads();
    for (int off = 1; off < BSZ; off <<= 1) {
        int add = (t < BSZ && t >= off) ? sc[t - off] : 0;
        __syncthreads();
        if (t < BSZ) sc[t] += add;
        __syncthreads();
    }
    if (t < BSZ) {
        int excl = sc[t] - v;
        hoff[t] = excl;  // cursor
        int node = node0 + t;
        if (node < n) {
            rowptr[node] = beg + excl;
            dinv[node] = rsqrtf((float)(v + 1));  // +1 self loop; always > 0
        }
    }
    __syncthreads();
    for (int i = beg + t; i < end; i += 256) {
        int pk = ebuf[i];
        int dloc = pk >> 20;
        int p = beg + atomicAdd(&hoff[dloc], 1);
        esrc[p] = pk & 0xFFFFF;
    }
}

// ================= GEMM1: P1 = (x @ W1) * dinv[row]  [N,128]x[128,64] =================

__global__ __launch_bounds__(256) void k_gemm1(const float* __restrict__ x,
                                               const float* __restrict__ W,
                                               const float* __restrict__ dinv,
                                               float* __restrict__ P, int n) {
    __shared__ float Ws[IN_DIM * HID];  // 32 KB
    const int t = threadIdx.x;
    {
        const float4* W4 = (const float4*)W;
        float4* Ws4 = (float4*)Ws;
#pragma unroll
        for (int i = 0; i < 8; ++i) Ws4[t + 256 * i] = W4[t + 256 * i];
    }
    __syncthreads();

    const int row0 = blockIdx.x * 64;
    const int ty = t >> 4, tx = t & 15;  // 4 rows x 4 cols per thread
    float acc[4][4];
#pragma unroll
    for (int i = 0; i < 4; ++i)
#pragma unroll
        for (int j = 0; j < 4; ++j) acc[i][j] = 0.f;

    const float4* x4 = (const float4*)x;
    int gr[4];
#pragma unroll
    for (int i = 0; i < 4; ++i) {
        int r = row0 + ty * 4 + i;
        gr[i] = r < n ? r : (n - 1);  // clamp for safe load; store is guarded
    }

#pragma unroll 2
    for (int k = 0; k < IN_DIM; k += 4) {
        float aa[4][4];
#pragma unroll
        for (int i = 0; i < 4; ++i) {
            float4 av = x4[(size_t)gr[i] * 32 + (k >> 2)];
            aa[i][0] = av.x; aa[i][1] = av.y; aa[i][2] = av.z; aa[i][3] = av.w;
        }
#pragma unroll
        for (int q = 0; q < 4; ++q) {
            float4 bv = *(const float4*)&Ws[(k + q) * HID + tx * 4];
#pragma unroll
            for (int i = 0; i < 4; ++i) {
                acc[i][0] = fmaf(aa[i][q], bv.x, acc[i][0]);
                acc[i][1] = fmaf(aa[i][q], bv.y, acc[i][1]);
                acc[i][2] = fmaf(aa[i][q], bv.z, acc[i][2]);
                acc[i][3] = fmaf(aa[i][q], bv.w, acc[i][3]);
            }
        }
    }

#pragma unroll
    for (int i = 0; i < 4; ++i) {
        int r = row0 + ty * 4 + i;
        if (r < n) {
            float s = dinv[r];
            float4 o = make_float4(acc[i][0] * s, acc[i][1] * s, acc[i][2] * s, acc[i][3] * s);
            *(float4*)&P[(size_t)r * HID + tx * 4] = o;
        }
    }
}

// ========== fused layer1 aggregation + GEMM2 (wave-local, no barrier, no LDS) ==========
// One 64-lane wave per node. After the xor-16/xor-32 butterfly EVERY lane holds the full
// aggregated sum for its chunk q, so every lane computes the relu'd h-fragment r.
// The P2 phase broadcasts h purely via __shfl from lanes 0..15 (h[k] lives in lane k>>2,
// component k&3): 64 shfl + 64 FMA + L1-resident W2 loads; lane c<40 stores P2[node][c].
// No __syncthreads -> waves retire independently (round-10 k_agg1 behavior preserved).

__global__ __launch_bounds__(256) void k_agg1f(const int* __restrict__ rowptr,
                                               const int* __restrict__ esrc,
                                               const float4* __restrict__ P4,
                                               const float* __restrict__ dinv,
                                               const float* __restrict__ b1,
                                               const float* __restrict__ W2,
                                               float* __restrict__ P2, int n) {
    const int t = threadIdx.x;
    const int lane = t & 63;
    const int node = blockIdx.x * 4 + (t >> 6);
    if (node >= n) return;
    const int grp = lane >> 4, q = lane & 15;  // 16 float4 = 64 feats
    const int beg = rowptr[node], end = rowptr[node + 1];

    float4 acc = make_float4(0.f, 0.f, 0.f, 0.f);
    int j = beg;
#pragma unroll 4
    for (; j + 3 < end; j += 4) {
        int s = esrc[j + grp];
        float4 v = P4[(size_t)s * 16 + q];
        acc.x += v.x; acc.y += v.y; acc.z += v.z; acc.w += v.w;
    }
    if (j + grp < end) {
        int s = esrc[j + grp];
        float4 v = P4[(size_t)s * 16 + q];
        acc.x += v.x; acc.y += v.y; acc.z += v.z; acc.w += v.w;
    }
    // butterfly combine: after this, all 4 groups hold identical full sums for chunk q
    acc.x += __shfl_xor(acc.x, 16); acc.y += __shfl_xor(acc.y, 16);
    acc.z += __shfl_xor(acc.z, 16); acc.w += __shfl_xor(acc.w, 16);
    acc.x += __shfl_xor(acc.x, 32); acc.y += __shfl_xor(acc.y, 32);
    acc.z += __shfl_xor(acc.z, 32); acc.w += __shfl_xor(acc.w, 32);

    // h-fragment (all lanes; self-row loads repeat grp0's addresses -> same L1 lines)
    const float di = dinv[node];
    float4 r;
    {
        float4 self = P4[(size_t)node * 16 + q];
        float4 bb = *(const float4*)&b1[q * 4];
        r.x = fmaxf(fmaf(di, acc.x + self.x, bb.x), 0.f);
        r.y = fmaxf(fmaf(di, acc.y + self.y, bb.y), 0.f);
        r.z = fmaxf(fmaf(di, acc.z + self.z, bb.z), 0.f);
        r.w = fmaxf(fmaf(di, acc.w + self.w, bb.w), 0.f);
    }

    // P2[node][c] = dinv * sum_k h[k] * W2[k][c]; h[k] broadcast from lane k>>2
    const int c = lane;  // lanes 0..39 active for store
    float s = 0.f;
#pragma unroll
    for (int q16 = 0; q16 < 16; ++q16) {
        float hx = __shfl(r.x, q16);
        float hy = __shfl(r.y, q16);
        float hz = __shfl(r.z, q16);
        float hw = __shfl(r.w, q16);
        const int k0 = q16 * 4;
        int cc = c < ODIM ? c : 0;  // clamp inactive lanes' addresses
        s = fmaf(hx, W2[(k0 + 0) * ODIM + cc], s);
        s = fmaf(hy, W2[(k0 + 1) * ODIM + cc], s);
        s = fmaf(hz, W2[(k0 + 2) * ODIM + cc], s);
        s = fmaf(hw, W2[(k0 + 3) * ODIM + cc], s);
    }
    if (c < ODIM) P2[(size_t)node * ODIM + c] = s * di;
}

// layer2 aggregation: 40 feats = 10 float4 per row (stride 160B, 16B aligned).
// 6 edge-slots x 10 chunks = 60 active lanes; 3-step combine lands on lanes 0..9.

__global__ __launch_bounds__(256) void k_agg2(const int* __restrict__ rowptr,
                                              const int* __restrict__ esrc,
                                              const float4* __restrict__ P4,
                                              const float* __restrict__ dinv,
                                              const float* __restrict__ b,
                                              float4* __restrict__ out4, int n) {
    const int t = threadIdx.x;
    const int lane = t & 63;
    const int node = blockIdx.x * 4 + (t >> 6);
    if (node >= n) return;
    const int grp = lane / 10;          // 0..6 (lanes 60-63: grp 6, inactive)
    const int q = lane - grp * 10;      // 0..9
    const bool act = grp < 6;
    const int beg = rowptr[node], end = rowptr[node + 1];

    float4 acc = make_float4(0.f, 0.f, 0.f, 0.f);
    int j = beg;
#pragma unroll 4
    for (; j + 5 < end; j += 6) {
        if (act) {
            int s = esrc[j + grp];
            float4 v = P4[(size_t)s * 10 + q];
            acc.x += v.x; acc.y += v.y; acc.z += v.z; acc.w += v.w;
        }
    }
    if (act && j + grp < end) {
        int s = esrc[j + grp];
        float4 v = P4[(size_t)s * 10 + q];
        acc.x += v.x; acc.y += v.y; acc.z += v.z; acc.w += v.w;
    }

    {
        float tx_ = __shfl(acc.x, lane + 30), ty_ = __shfl(acc.y, lane + 30);
        float tz_ = __shfl(acc.z, lane + 30), tw_ = __shfl(acc.w, lane + 30);
        if (lane < 30) { acc.x += tx_; acc.y += ty_; acc.z += tz_; acc.w += tw_; }
    }
    {
        float tx_ = __shfl(acc.x, lane + 20), ty_ = __shfl(acc.y, lane + 20);
        float tz_ = __shfl(acc.z, lane + 20), tw_ = __shfl(acc.w, lane + 20);
        if (lane < 10) { acc.x += tx_; acc.y += ty_; acc.z += tz_; acc.w += tw_; }
    }
    {
        float tx_ = __shfl(acc.x, lane + 10), ty_ = __shfl(acc.y, lane + 10);
        float tz_ = __shfl(acc.z, lane + 10), tw_ = __shfl(acc.w, lane + 10);
        if (lane < 10) { acc.x += tx_; acc.y += ty_; acc.z += tz_; acc.w += tw_; }
    }

    if (lane < 10) {  // full sums live here
        float4 self = P4[(size_t)node * 10 + q];
        float di = dinv[node];
        float4 bb = *(const float4*)&b[q * 4];
        float4 r;
        r.x = fmaf(di, acc.x + self.x, bb.x);
        r.y = fmaf(di, acc.y + self.y, bb.y);
        r.z = fmaf(di, acc.z + self.z, bb.z);
        r.w = fmaf(di, acc.w + self.w, bb.w);
        out4[(size_t)node * 10 + q] = r;  // 10 lanes: 160B store
    }
}

// ================= launch =================

extern "C" void kernel_launch(void* const* d_in, const int* in_sizes, int n_in,
                              void* d_out, int out_size, void* d_ws, size_t ws_size,
                              hipStream_t stream) {
    const float* x  = (const float*)d_in[0];
    const int*   ei = (const int*)d_in[1];
    const float* W1 = (const float*)d_in[2];
    const float* b1 = (const float*)d_in[3];
    const float* W2 = (const float*)d_in[4];
    const float* b2 = (const float*)d_in[5];

    const int n = in_sizes[0] / IN_DIM;   // 100000
    const int e = in_sizes[1] / 2;        // 1600000
    const int* src = ei;
    const int* dst = ei + e;
    const int nb = (n + BSZ - 1) >> BSH;  // 782
    const int total = nb * NBLK;          // ~200K
    const int nchunks = (total + SCH - 1) / SCH;  // 98

    auto align = [](size_t b) { return (b + 255) & ~(size_t)255; };
    char* ws = (char*)d_ws;
    size_t o = 0;
    int*   histM = (int*)(ws + o);   o += align((size_t)NBMAX * NBLK * 4);  // 1 MB
    int*   offM  = (int*)(ws + o);   o += align((size_t)NBMAX * NBLK * 4);  // 1 MB
    int*   csum  = (int*)(ws + o);   o += align((size_t)256 * 4);
    int*   bbase = (int*)(ws + o);   o += align((size_t)NBMAX * 4);
    float* dinv  = (float*)(ws + o); o += align((size_t)n * 4);
    int*   rowptr= (int*)(ws + o);   o += align((size_t)(n + 1) * 4);
    int*   ebuf  = (int*)(ws + o);   o += align((size_t)e * 4);             // 6.4 MB
    int*   esrc  = (int*)(ws + o);   o += align((size_t)e * 4);             // 6.4 MB
    float* P1    = (float*)(ws + o); o += align((size_t)n * HID * 4);       // 25.6 MB
    float* P2    = (float*)(ws + o); o += align((size_t)n * ODIM * 4);      // 16 MB
    // total ~58 MB; no memset needed (all buffers fully written each call)

    float* out = (float*)d_out;

    // ---- radix-partition CSR build (no global atomics, hierarchical scan) ----
    k_hist<<<NBLK, 256, 0, stream>>>(dst, histM, e, nb);
    k_s1<<<nchunks, 256, 0, stream>>>(histM, csum, total);
    k_s2<<<1, 256, 0, stream>>>(csum, nchunks, rowptr, n, e);
    k_s3<<<nchunks, 256, 0, stream>>>(histM, csum, offM, bbase, total);
    k_bscatter2<<<NBLK, 256, 0, stream>>>(src, dst, offM, ebuf, e, nb);
    k_bsort<<<nb, 256, 0, stream>>>(ebuf, bbase, esrc, rowptr, dinv, n, nb, e);

    // ---- layer 1 (GEMM) ----
    k_gemm1<<<(n + 63) / 64, 256, 0, stream>>>(x, W1, dinv, P1, n);

    // ---- fused layer-1 aggregation + layer-2 transform (wave-local) ----
    k_agg1f<<<(n + 3) / 4, 256, 0, stream>>>(rowptr, esrc, (const float4*)P1, dinv, b1,
                                             W2, P2, n);

    // ---- layer-2 aggregation (final output) ----
    k_agg2<<<(n + 3) / 4, 256, 0, stream>>>(rowptr, esrc, (const float4*)P2, dinv, b2,
                                            (float4*)out, n);
}